// Round 6
// baseline (2697.051 us; speedup 1.0000x reference)
//
#include <hip/hip_runtime.h>
#include <math.h>

#define S_LEN 1024
#define BATCH 2048
#define HID   128
#define MTILE 16
#define NBLK  (BATCH / MTILE)   // 128 blocks
#define INV2048 (1.0f / 2048.0f)

// ws layout, offsets in _Float16 elements. K-extended arrays are [128][160]:
// k<128 = real weights, k=128..130 = (bias, x0-coef, x1-coef), k=131..159 = 0.
#define H_M1H 0
#define H_M1L 20480
#define H_MSH 40960
#define H_MSL 61440
#define H_ASH 81920
#define H_ASL 102400
#define H_WMH 122880     // [128][128] WtauM[:,128:256] hi
#define H_WML 139264
#define H_WBH 155648     // [128][128] WtauAdp[:,128:256] hi
#define H_WBL 172032
#define OFF_PART_F 94208 // float index into ws for per-block partials

typedef _Float16 half8 __attribute__((ext_vector_type(8)));
typedef _Float16 half4 __attribute__((ext_vector_type(4)));
typedef float floatx4 __attribute__((ext_vector_type(4)));

#define MFMA(a, b, c) __builtin_amdgcn_mfma_f32_16x16x32_f16((a), (b), (c), 0, 0, 0)

__device__ __forceinline__ void put_hl(_Float16* ws, int hiBase, int loBase,
                                       int idx, float v) {
  _Float16 hi = (_Float16)v;
  ws[hiBase + idx] = hi;
  ws[loBase + idx] = (_Float16)((v - (float)hi) * 2048.0f);
}

// ---- prep: fold dense->tau coupling + all per-h scalars into f16 hi/lo
// fragment-ready arrays.
__global__ __launch_bounds__(192) void prep(
    const float* __restrict__ W1x, const float* __restrict__ b1x,
    const float* __restrict__ WtauM, const float* __restrict__ btauM,
    const float* __restrict__ WtauAdp, const float* __restrict__ btauAdp,
    _Float16* __restrict__ ws) {
  const int h = blockIdx.x, k = threadIdx.x;
  if (k >= 160) return;
  if (k < 128) {
    float w1 = W1x[h * 130 + 2 + k];
    float s1 = 0.f, s2 = 0.f;
    for (int d = 0; d < 128; ++d) {
      float wd = W1x[d * 130 + 2 + k];
      s1 += WtauM[h * 256 + d] * wd;
      s2 += WtauAdp[h * 256 + d] * wd;
    }
    put_hl(ws, H_M1H, H_M1L, h * 160 + k, w1);
    put_hl(ws, H_MSH, H_MSL, h * 160 + k, s1);
    put_hl(ws, H_ASH, H_ASL, h * 160 + k, s2);
    put_hl(ws, H_WMH, H_WML, h * 128 + k, WtauM[h * 256 + 128 + k]);
    put_hl(ws, H_WBH, H_WBL, h * 128 + k, WtauAdp[h * 256 + 128 + k]);
  } else if (k < 131) {
    const int col = k - 128;   // 0: bias, 1: x0-coef, 2: x1-coef
    float m1v = (col == 0) ? b1x[h] : W1x[h * 130 + (col - 1)];
    float sm = 0.f, sa = 0.f;
    for (int d = 0; d < 128; ++d) {
      float cv = (col == 0) ? b1x[d] : W1x[d * 130 + (col - 1)];
      sm += WtauM[h * 256 + d] * cv;
      sa += WtauAdp[h * 256 + d] * cv;
    }
    if (col == 0) { sm += btauM[h]; sa += btauAdp[h]; }
    put_hl(ws, H_M1H, H_M1L, h * 160 + k, m1v);
    put_hl(ws, H_MSH, H_MSL, h * 160 + k, sm);
    put_hl(ws, H_ASH, H_ASL, h * 160 + k, sa);
  } else {
    put_hl(ws, H_M1H, H_M1L, h * 160 + k, 0.f);
    put_hl(ws, H_MSH, H_MSL, h * 160 + k, 0.f);
    put_hl(ws, H_ASH, H_ASL, h * 160 + k, 0.f);
  }
}

// State planes in MFMA B-fragment slab order: slab f (1 KB) holds, at
// half-index lane*8, B[n=lane&15][k=f*32+(lane>>4)*8 .. +8) -> every
// ds_read_b128 is lane-contiguous. bx slabs hold the per-step [1,x0,x1,0..]
// K-extension operand (hi/lo).
struct SLds {
  _Float16 spk[2][2048];
  _Float16 mH[2][2048], mL[2][2048];
  _Float16 bH[2][2048], bL[2][2048];
  _Float16 bxh[2][512], bxl[2][512];
  float red[4][16];
  float red2[16];
};

__global__ __launch_bounds__(256, 1) void snn_main(
    const float* __restrict__ x, const float* __restrict__ y,
    const float* __restrict__ h0m, const float* __restrict__ h0s,
    const float* __restrict__ h0b,
    const float* __restrict__ Wlin, const float* __restrict__ blin,
    const _Float16* __restrict__ W, float* __restrict__ wsout) {
  __shared__ SLds L;

  const int tid  = threadIdx.x;
  const int w    = tid >> 6;      // wave 0..3, owns h-slice [32w, 32w+32)
  const int lane = tid & 63;
  const int c    = lane & 15;
  const int q    = lane >> 4;
  const int bbase = blockIdx.x * MTILE;

  // ---- Register-resident A-frag weights (AGPR-eligible: only MFMA reads them)
  half8 m1h[2][5], m1l[2][5];
  half8 msh[2][5], msl[2][5];
  half8 ash[2][5], asl[2][5];
  half8 wmh[2][4], wml[2][4];
  half8 wbh[2][4], wbl[2][4];
#pragma unroll
  for (int s = 0; s < 2; ++s) {
    const int hA = w * 32 + s * 16 + c;
#pragma unroll
    for (int f = 0; f < 5; ++f) {
      const int o = hA * 160 + f * 32 + q * 8;
      m1h[s][f] = *(const half8*)&W[H_M1H + o];
      m1l[s][f] = *(const half8*)&W[H_M1L + o];
      msh[s][f] = *(const half8*)&W[H_MSH + o];
      msl[s][f] = *(const half8*)&W[H_MSL + o];
      ash[s][f] = *(const half8*)&W[H_ASH + o];
      asl[s][f] = *(const half8*)&W[H_ASL + o];
    }
#pragma unroll
    for (int f = 0; f < 4; ++f) {
      const int o = hA * 128 + f * 32 + q * 8;
      wmh[s][f] = *(const half8*)&W[H_WMH + o];
      wml[s][f] = *(const half8*)&W[H_WML + o];
      wbh[s][f] = *(const half8*)&W[H_WBH + o];
      wbl[s][f] = *(const half8*)&W[H_WBL + o];
    }
  }

  // ---- Per-lane recurrent state in C layout: (h = w*32+s*16+q*4+r, b = c)
  float memv[8], spk[8], bb[8];
#pragma unroll
  for (int s = 0; s < 2; ++s) {
#pragma unroll
    for (int r = 0; r < 4; ++r) {
      const int i = s * 4 + r;
      const int gi = (bbase + c) * HID + w * 32 + s * 16 + q * 4 + r;
      memv[i] = h0m[gi]; spk[i] = h0s[gi]; bb[i] = h0b[gi];
    }
  }

  // ---- Zero bx slabs (4 KB = 2048 halves; one half8 per thread)
  { _Float16* bz = (_Float16*)L.bxh;
    *(half8*)&bz[tid * 8] = half8{0,0,0,0,0,0,0,0}; }

  // ---- Initialize plane buf 0 in slab order (waves split the 3 state units)
  for (int u = w; u < 3; u += 4) {
    const float* src = (u == 0) ? h0s : (u == 1) ? h0m : h0b;
#pragma unroll
    for (int f = 0; f < 4; ++f) {
      const int gbase = (bbase + c) * HID + f * 32 + q * 8;
      half8 hi8, lo8;
#pragma unroll
      for (int j = 0; j < 8; ++j) {
        float v = src[gbase + j];
        _Float16 hi = (_Float16)v;
        hi8[j] = hi; lo8[j] = (_Float16)((v - (float)hi) * 2048.0f);
      }
      const int off = f * 512 + lane * 8;
      if (u == 0) { *(half8*)&L.spk[0][off] = hi8; }
      else if (u == 1) { *(half8*)&L.mH[0][off] = hi8; *(half8*)&L.mL[0][off] = lo8; }
      else { *(half8*)&L.bH[0][off] = hi8; *(half8*)&L.bL[0][off] = lo8; }
    }
  }
  __syncthreads();   // bx zeros + planes visible before bx[0] value writes

  float2 xcur = *(const float2*)&x[(size_t)(bbase + c) * 2];
  if (tid < 16) {
    _Float16 x0h = (_Float16)xcur.x, x1h = (_Float16)xcur.y;
    half8 bh = {(_Float16)1.0f, x0h, x1h, 0, 0, 0, 0, 0};
    half8 bl = {0, (_Float16)((xcur.x - (float)x0h) * 2048.0f),
                   (_Float16)((xcur.y - (float)x1h) * 2048.0f), 0, 0, 0, 0, 0};
    *(half8*)&L.bxh[0][tid * 8] = bh;
    *(half8*)&L.bxl[0][tid * 8] = bl;
  }

  // Write offsets (slab order) for this lane's C rows, per s: constant over t
  int wo[2];
#pragma unroll
  for (int s = 0; s < 2; ++s)
    wo[s] = w * 512 + ((s * 2 + (q >> 1)) * 16 + c) * 8 + (q & 1) * 4;

  __syncthreads();

#pragma unroll 1
  for (int t = 0; t < S_LEN; ++t) {
    const int p = t & 1, pn = p ^ 1;
    const int rb = lane * 8;

    floatx4 dh[2] = {{0.f,0.f,0.f,0.f},{0.f,0.f,0.f,0.f}};
    floatx4 dl[2] = {{0.f,0.f,0.f,0.f},{0.f,0.f,0.f,0.f}};
    floatx4 mh[2] = {{0.f,0.f,0.f,0.f},{0.f,0.f,0.f,0.f}};
    floatx4 ml[2] = {{0.f,0.f,0.f,0.f},{0.f,0.f,0.f,0.f}};
    floatx4 ah[2] = {{0.f,0.f,0.f,0.f},{0.f,0.f,0.f,0.f}};
    floatx4 al[2] = {{0.f,0.f,0.f,0.f},{0.f,0.f,0.f,0.f}};

#pragma unroll
    for (int f = 0; f < 4; ++f) {
      const int off = f * 512 + rb;
      half8 bs  = *(const half8*)&L.spk[p][off];
      half8 xmh = *(const half8*)&L.mH[p][off];
      half8 xml = *(const half8*)&L.mL[p][off];
      half8 xbh = *(const half8*)&L.bH[p][off];
      half8 xbl = *(const half8*)&L.bL[p][off];
#pragma unroll
      for (int s = 0; s < 2; ++s) {
        dh[s] = MFMA(m1h[s][f], bs, dh[s]);
        dl[s] = MFMA(m1l[s][f], bs, dl[s]);
        mh[s] = MFMA(msh[s][f], bs, mh[s]);
        ml[s] = MFMA(msl[s][f], bs, ml[s]);
        mh[s] = MFMA(wmh[s][f], xmh, mh[s]);
        ml[s] = MFMA(wmh[s][f], xml, ml[s]);
        ml[s] = MFMA(wml[s][f], xmh, ml[s]);
        ah[s] = MFMA(ash[s][f], bs, ah[s]);
        al[s] = MFMA(asl[s][f], bs, al[s]);
        ah[s] = MFMA(wbh[s][f], xbh, ah[s]);
        al[s] = MFMA(wbh[s][f], xbl, al[s]);
        al[s] = MFMA(wbl[s][f], xbh, al[s]);
      }
    }
    {  // K-extension chunk: bias + x coupling via [1,x0,x1] fragment
      half8 bxh8 = *(const half8*)&L.bxh[p][rb];
      half8 bxl8 = *(const half8*)&L.bxl[p][rb];
#pragma unroll
      for (int s = 0; s < 2; ++s) {
        dh[s] = MFMA(m1h[s][4], bxh8, dh[s]);
        dl[s] = MFMA(m1l[s][4], bxh8, dl[s]);
        dl[s] = MFMA(m1h[s][4], bxl8, dl[s]);
        mh[s] = MFMA(msh[s][4], bxh8, mh[s]);
        ml[s] = MFMA(msl[s][4], bxh8, ml[s]);
        ml[s] = MFMA(msh[s][4], bxl8, ml[s]);
        ah[s] = MFMA(ash[s][4], bxh8, ah[s]);
        al[s] = MFMA(asl[s][4], bxh8, al[s]);
        al[s] = MFMA(ash[s][4], bxl8, al[s]);
      }
    }

    // prefetch next x (clamped address, always valid)
    const size_t tn = (t + 1 < S_LEN) ? (size_t)(t + 1) : (size_t)t;
    float2 xnext = *(const float2*)&x[(tn * BATCH + bbase + c) * 2];

    // ---- Elementwise update + packed b64 slab writes
#pragma unroll
    for (int s = 0; s < 2; ++s) {
      half4 ps, mh4, ml4, bh4, bl4;
#pragma unroll
      for (int r = 0; r < 4; ++r) {
        const int i = s * 4 + r;
        float den  = dh[s][r] + dl[s][r] * INV2048;
        float preM = mh[s][r] + ml[s][r] * INV2048;
        float preA = ah[s][r] + al[s][r] * INV2048;
        float tM = __builtin_amdgcn_rcpf(1.0f + __expf(-preM));
        float tA = __builtin_amdgcn_rcpf(1.0f + __expf(-preA));
        bb[i] = tA * bb[i] + (1.0f - tA) * spk[i];
        float Bth = 0.01f + 1.8f * bb[i];
        memv[i] = memv[i] * tM + (1.0f - tM) * den - Bth * spk[i];
        spk[i] = (memv[i] - Bth) > 0.0f ? 1.0f : 0.0f;
        ps[r] = (_Float16)spk[i];
        float v = memv[i]; _Float16 hi = (_Float16)v;
        mh4[r] = hi; ml4[r] = (_Float16)((v - (float)hi) * 2048.0f);
        v = bb[i]; hi = (_Float16)v;
        bh4[r] = hi; bl4[r] = (_Float16)((v - (float)hi) * 2048.0f);
      }
      *(half4*)&L.spk[pn][wo[s]] = ps;
      *(half4*)&L.mH[pn][wo[s]] = mh4; *(half4*)&L.mL[pn][wo[s]] = ml4;
      *(half4*)&L.bH[pn][wo[s]] = bh4; *(half4*)&L.bL[pn][wo[s]] = bl4;
    }
    if (tid < 16) {   // stage next step's K-extension fragment
      _Float16 x0h = (_Float16)xnext.x, x1h = (_Float16)xnext.y;
      half8 bhx = {(_Float16)1.0f, x0h, x1h, 0, 0, 0, 0, 0};
      half8 blx = {0, (_Float16)((xnext.x - (float)x0h) * 2048.0f),
                      (_Float16)((xnext.y - (float)x1h) * 2048.0f), 0, 0, 0, 0, 0};
      *(half8*)&L.bxh[pn][tid * 8] = bhx;
      *(half8*)&L.bxl[pn][tid * 8] = blx;
    }
    xcur = xnext;
    __syncthreads();
  }

  // ---- Readout: out[b] = mem[b,:] @ Wlin + blin; per-block loss partial
  float part = 0.0f;
#pragma unroll
  for (int s = 0; s < 2; ++s)
#pragma unroll
    for (int r = 0; r < 4; ++r)
      part += memv[s * 4 + r] * Wlin[w * 32 + s * 16 + q * 4 + r];
  part += __shfl_xor(part, 16);
  part += __shfl_xor(part, 32);
  if (lane < 16) L.red[w][c] = part;
  __syncthreads();
  if (tid < 16) {
    float s = L.red[0][tid] + L.red[1][tid] + L.red[2][tid] + L.red[3][tid];
    float out = s + blin[0];
    float d = out - y[bbase + tid];
    L.red2[tid] = d * d;
  }
  __syncthreads();
  if (tid == 0) {
    float s = 0.0f;
#pragma unroll
    for (int m = 0; m < 16; ++m) s += L.red2[m];
    wsout[blockIdx.x] = s;
  }
}

__global__ __launch_bounds__(128) void final_reduce(const float* __restrict__ part,
                                                    float* __restrict__ out) {
  __shared__ float sh[128];
  int t = threadIdx.x;
  sh[t] = part[t];
  __syncthreads();
  for (int s = 64; s > 0; s >>= 1) {
    if (t < s) sh[t] += sh[t + s];
    __syncthreads();
  }
  if (t == 0) out[0] = sh[0] * (1.0f / (float)BATCH);
}

extern "C" void kernel_launch(void* const* d_in, const int* in_sizes, int n_in,
                              void* d_out, int out_size, void* d_ws, size_t ws_size,
                              hipStream_t stream) {
  const float* x       = (const float*)d_in[0];
  const float* y       = (const float*)d_in[1];
  const float* h0m     = (const float*)d_in[2];
  const float* h0s     = (const float*)d_in[3];
  const float* h0b     = (const float*)d_in[4];
  const float* W1x     = (const float*)d_in[5];
  const float* b1x     = (const float*)d_in[6];
  const float* WtauM   = (const float*)d_in[7];
  const float* btauM   = (const float*)d_in[8];
  const float* WtauAdp = (const float*)d_in[9];
  const float* btauAdp = (const float*)d_in[10];
  const float* Wlin    = (const float*)d_in[11];
  const float* blin    = (const float*)d_in[12];
  _Float16* wsf16 = (_Float16*)d_ws;
  float* wspart = (float*)d_ws + OFF_PART_F;

  prep<<<128, 192, 0, stream>>>(W1x, b1x, WtauM, btauM, WtauAdp, btauAdp, wsf16);
  snn_main<<<NBLK, 256, 0, stream>>>(x, y, h0m, h0s, h0b, Wlin, blin,
                                     wsf16, wspart);
  final_reduce<<<1, 128, 0, stream>>>(wspart, (float*)d_out);
}